// Round 8
// baseline (270.394 us; speedup 1.0000x reference)
//
#include <hip/hip_runtime.h>
#include <hip/hip_bf16.h>

// LSTM B=8192,T=512,I=3,H=25 + linear[H->1], bf16 MFMA 16x16x32.
// R20: TWO CHAINS, ONE BLOCK - kill the inter-block phase-lock.
// R19 post-mortem: period 914/step-pair with 2 blocks/CU; per-SIMD issue
// only 521 (57%) because the two blocks' barriers phase-lock and both
// stall through the read->MFMA->acts window together. Fix: merge the CU's
// two chains into ONE 512-thread block: waves 0-3 = chain A (batches
// 0..15), waves 4-7 = chain B (16..31); each wave keeps R19's workload
// (2 row-blocks, 14 trans, frag-linear LDS, pad-slot writes). Now every
// SIMD hosts one A-wave + one B-wave with INDEPENDENT streams -> the
// trans pipe gets 28 instrs/period (448cy) with mutual bubble-fill, and
// one barrier serves both chains. 256 blocks = 1 block/CU (deterministic
// co-scheduling, no dispatch lottery).
// Kept from R19: register A-frags with -K1/-K2 prescale, x-insert from
// registers (q0 lanes), merged-denominator c-update, v2f pk glue,
// lgkmcnt-only raw barrier (x prefetch stays in flight), parity buffers.

#define TSTEPS 512
#define ISZ 3
#define HSZ 25

typedef __attribute__((ext_vector_type(8))) short bf16x8;
typedef __attribute__((ext_vector_type(4))) float f32x4;
typedef __attribute__((ext_vector_type(4))) int i32x4;
typedef __attribute__((ext_vector_type(2))) float v2f;

__device__ __forceinline__ unsigned short bf16_bits(float v) {
    return __builtin_bit_cast(unsigned short, __float2bfloat16(v));
}
__device__ __forceinline__ unsigned int pack_bf16(float lo, float hi) {
    return ((unsigned int)bf16_bits(hi) << 16) | (unsigned int)bf16_bits(lo);
}
__device__ __forceinline__ v2f rcp2(v2f v) {
    return (v2f){__builtin_amdgcn_rcpf(v.x), __builtin_amdgcn_rcpf(v.y)};
}

__global__ __launch_bounds__(512, 2) void lstm_mfma(
    const float* __restrict__ x,      // [B, T, I]
    const float* __restrict__ w_ih,   // [4H, I]
    const float* __restrict__ w_hh,   // [4H, H]
    const float* __restrict__ b_ih,   // [4H]
    const float* __restrict__ b_hh,   // [4H]
    const float* __restrict__ w_lin,  // [1, H]
    const float* __restrict__ b_lin,  // [1]
    float* __restrict__ out)          // [B, 1]
{
    // frag-linear: short idx (k,n) = (k>>3)*128 + n*8 + (k&7); idx 0..511 is
    // the real frag (k<32); 512..767 scrap for row-block-7 writes (kw<=35).
    __shared__ short hb[2][2][768];       // [chain][parity]
    __shared__ float outred[8][16];

    const int tid  = threadIdx.x;
    const int w    = tid >> 6;        // wave 0..7
    const int lane = tid & 63;
    const int n    = lane & 15;       // batch col within chain
    const int q    = lane >> 4;       // quad -> k-slots 8q..8q+7
    const int ch   = w >> 2;          // chain 0 (batches 0-15) / 1 (16-31)
    const int wv   = w & 3;           // row-block set within chain
    const int b0   = blockIdx.x * 32;

    const float K1 = 1.442695040888963f;   // log2 e
    const float K2 = 2.885390081777927f;   // 2 log2 e

    if (tid < 384) ((int4*)hb)[tid] = (int4){0, 0, 0, 0};   // 6144 B zeroed

    // ---- A fragments for row-blocks jbA=wv, jbB=wv+4 (rows >=25 zero) ----
    // Within a block: MFMA row rr=n -> unit 4*jb + (n>>2), gate n&3.
    // k map: 0..2 w_ih, 3 bias, 4..28 w_hh col k-4, 29..31 pad.
    bf16x8 afA, afB;
    {
        const int g = n & 3, us = n >> 2;
        const int uA = 4 * wv + us;           // <= 15, always valid
        const int uB = 4 * (wv + 4) + us;     // 16..31, guard < 25
        #pragma unroll
        for (int j = 0; j < 8; ++j) {
            const int k = q * 8 + j;
            float vA = 0.f, vB = 0.f;
            {
                const int orow = g * HSZ + uA;
                if (k < ISZ)            vA = w_ih[orow * ISZ + k];
                else if (k == ISZ)      vA = b_ih[orow] + b_hh[orow];
                else if (k < 4 + HSZ)   vA = w_hh[orow * HSZ + (k - 4)];
                vA *= (g == 2) ? -K2 : -K1;
            }
            if (uB < HSZ) {
                const int orow = g * HSZ + uB;
                if (k < ISZ)            vB = w_ih[orow * ISZ + k];
                else if (k == ISZ)      vB = b_ih[orow] + b_hh[orow];
                else if (k < 4 + HSZ)   vB = w_hh[orow * HSZ + (k - 4)];
                vB *= (g == 2) ? -K2 : -K1;
            }
            afA[j] = (short)bf16_bits(vA);
            afB[j] = (short)bf16_bits(vB);
        }
    }

    // ---- write slots: unit u=4jb+q -> k=u+4 (pads/scrap land harmlessly) --
    const int uwA = 4 * wv + q;                // <= 15
    const int uwB = 4 * (wv + 4) + q;          // 16..31 (>=25 -> pad/scrap)
    const int kwA = uwA + 4, kwB = uwB + 4;    // kwB <= 35 -> scrap region
    const int woffA = (kwA >> 3) * 128 + n * 8 + (kwA & 7);
    const int woffB = (kwB >> 3) * 128 + n * 8 + (kwB & 7);
    const int rdoff = lane * 8;

    v2f c = {0.f, 0.f}, h = {0.f, 0.f};

    // ---- x prefetch: 3 x float4 per 4-step group, reg ping-pong ----
    const float* __restrict__ xg =
        x + (size_t)(b0 + ch * 16 + n) * (TSTEPS * ISZ);
    float4 a0 = ((const float4*)xg)[0];
    float4 a1 = ((const float4*)xg)[1];
    float4 a2 = ((const float4*)xg)[2];

    __syncthreads();   // zeros visible (drains first prefetch once - ok)

    auto step = [&](int rp, float x0, float x1, float x2) {
        // linear ds_read_b128 from this chain's buffer; q0 lanes insert x
        bf16x8 frag = *(const bf16x8*)&hb[ch][rp][rdoff];
        i32x4 fi = __builtin_bit_cast(i32x4, frag);
        const int px0 = (int)pack_bf16(x0, x1);
        const int px1 = (int)pack_bf16(x2, 1.0f);
        fi[0] = (q == 0) ? px0 : fi[0];
        fi[1] = (q == 0) ? px1 : fi[1];
        frag = __builtin_bit_cast(bf16x8, fi);

        const f32x4 zc = {0.f, 0.f, 0.f, 0.f};
        const f32x4 aA = __builtin_amdgcn_mfma_f32_16x16x32_bf16(afA, frag, zc, 0, 0, 0);
        const f32x4 aB = __builtin_amdgcn_mfma_f32_16x16x32_bf16(afB, frag, zc, 0, 0, 0);

        // acts (prescaled): 14 trans; glue packed v2f across (A,B) blocks
        const v2f e0 = {__builtin_amdgcn_exp2f(aA[0]), __builtin_amdgcn_exp2f(aB[0])};
        const v2f e1 = {__builtin_amdgcn_exp2f(aA[1]), __builtin_amdgcn_exp2f(aB[1])};
        const v2f e2 = {__builtin_amdgcn_exp2f(fminf(aA[2], 126.f)),
                        __builtin_amdgcn_exp2f(fminf(aB[2], 126.f))};
        const v2f e3 = {__builtin_amdgcn_exp2f(aA[3]), __builtin_amdgcn_exp2f(aB[3])};
        const v2f one = {1.f, 1.f};
        const v2f s0 = e0 + one, s1 = e1 + one, s2 = e2 + one, m2 = one - e2;
        const v2f p02 = s0 * s2;
        const v2f num = c * p02 + m2 * s1;     // merged-denominator c-update
        const v2f den = p02 * s1;
        c = num * rcp2(den);
        const v2f ec = {__builtin_amdgcn_exp2f(fminf(-K2 * c.x, 126.f)),
                        __builtin_amdgcn_exp2f(fminf(-K2 * c.y, 126.f))};
        const v2f hden = (e3 + one) * (ec + one);
        h = (one - ec) * rcp2(hden);

        const int wp = rp ^ 1;
        hb[ch][wp][woffA] = (short)bf16_bits(h.x);
        hb[ch][wp][woffB] = (short)bf16_bits(h.y);   // pad/scrap-slot trick
        // retire DS writes, then barrier; vmcnt (x prefetch) stays in flight
        asm volatile("s_waitcnt lgkmcnt(0)" ::: "memory");
        __builtin_amdgcn_s_barrier();
    };

    #pragma unroll 1
    for (int g = 0; g < 128; g += 2) {
        const float4* __restrict__ p1 =
            (const float4*)(xg + (size_t)((g + 1 < 128 ? g + 1 : 127) * 12));
        const float4 n0 = p1[0], n1 = p1[1], n2 = p1[2];
        step(0, a0.x, a0.y, a0.z);
        step(1, a0.w, a1.x, a1.y);
        step(0, a1.z, a1.w, a2.x);
        step(1, a2.y, a2.z, a2.w);
        const float4* __restrict__ p2 =
            (const float4*)(xg + (size_t)((g + 2 < 128 ? g + 2 : 127) * 12));
        a0 = p2[0]; a1 = p2[1]; a2 = p2[2];
        step(0, n0.x, n0.y, n0.z);
        step(1, n0.w, n1.x, n1.y);
        step(0, n1.z, n1.w, n2.x);
        step(1, n2.y, n2.z, n2.w);
    }

    // ---- final linear: out[b] = sum_u w_lin[u]*h[u] + b_lin ----
    const float wlA = (uwA < HSZ) ? w_lin[uwA] : 0.f;
    const float wlB = (uwB < HSZ) ? w_lin[uwB] : 0.f;
    float v = wlA * h.x + wlB * h.y;
    v += __shfl_xor(v, 16);
    v += __shfl_xor(v, 32);
    if (lane < 16) outred[w][lane] = v;
    __syncthreads();
    if (tid < 32) {
        const int c2 = tid >> 4;          // chain of this output batch
        float s = b_lin[0];
        #pragma unroll
        for (int k2 = 0; k2 < 4; ++k2) s += outred[c2 * 4 + k2][tid & 15];
        out[b0 + tid] = s;
    }
}

extern "C" void kernel_launch(void* const* d_in, const int* in_sizes, int n_in,
                              void* d_out, int out_size, void* d_ws, size_t ws_size,
                              hipStream_t stream) {
    const float* x     = (const float*)d_in[0];
    const float* w_ih  = (const float*)d_in[1];
    const float* w_hh  = (const float*)d_in[2];
    const float* b_ih  = (const float*)d_in[3];
    const float* b_hh  = (const float*)d_in[4];
    const float* w_lin = (const float*)d_in[5];
    const float* b_lin = (const float*)d_in[6];
    float* out = (float*)d_out;

    lstm_mfma<<<8192 / 32, 512, 0, stream>>>(x, w_ih, w_hh, b_ih, b_hh,
                                             w_lin, b_lin, out);
}

// Round 9
// 256.960 us; speedup vs baseline: 1.0523x; 1.0523x over previous
//
#include <hip/hip_runtime.h>
#include <hip/hip_bf16.h>

// LSTM B=8192,T=512,I=3,H=25 + linear[H->1], bf16 MFMA 16x16x32.
// R21 = R19 + ANTI-PHASE STAGGER. R20 post-mortem: period = per-SIMD issue
// (515cy) + chain (~430cy) with ZERO overlap, because co-scheduled waves are
// released by the same barrier running identical code -> issue bursts and
// stall windows coincide. R19's two co-resident blocks start in-phase at
// launch and relative phase is neutrally stable -> locked forever. Fix: give
// one block of each co-resident pair a one-time ~450cy s_sleep before the
// main loop. The half-period offset is conserved (identical periods), so
// each block's issue-dense window covers the other's read->MFMA->acts chain
// window on the shared SIMDs. Pair-parity ((blockIdx>>8)^blockIdx)&1 yields
// opposite phases under both plausible dispatch mappings ((2i,2i+1) and
// (i,i+256) for 512 blocks / 8 XCDs round-robin).
// Everything else identical to R19 (195us measured): 4-wave blocks, 1 chain
// per block, per-wave 2 MFMA row-blocks, frag-linear LDS, merged-denominator
// c-update, v2f pk glue, lgkmcnt-only barrier, register x ping-pong.

#define TSTEPS 512
#define ISZ 3
#define HSZ 25

typedef __attribute__((ext_vector_type(8))) short bf16x8;
typedef __attribute__((ext_vector_type(4))) float f32x4;
typedef __attribute__((ext_vector_type(4))) int i32x4;
typedef __attribute__((ext_vector_type(2))) float v2f;

__device__ __forceinline__ unsigned short bf16_bits(float v) {
    return __builtin_bit_cast(unsigned short, __float2bfloat16(v));
}
__device__ __forceinline__ unsigned int pack_bf16(float lo, float hi) {
    return ((unsigned int)bf16_bits(hi) << 16) | (unsigned int)bf16_bits(lo);
}
__device__ __forceinline__ v2f rcp2(v2f v) {
    return (v2f){__builtin_amdgcn_rcpf(v.x), __builtin_amdgcn_rcpf(v.y)};
}

__global__ __launch_bounds__(256, 2) void lstm_mfma(
    const float* __restrict__ x,      // [B, T, I]
    const float* __restrict__ w_ih,   // [4H, I]
    const float* __restrict__ w_hh,   // [4H, H]
    const float* __restrict__ b_ih,   // [4H]
    const float* __restrict__ b_hh,   // [4H]
    const float* __restrict__ w_lin,  // [1, H]
    const float* __restrict__ b_lin,  // [1]
    float* __restrict__ out)          // [B, 1]
{
    // frag-linear: short idx (k,n) = (k>>3)*128 + n*8 + (k&7); real frag is
    // idx 0..511 (k<32); 512..767 is scrap for the jb=7 block's writes.
    __shared__ short hb[2][768];
    __shared__ float outred[4][16];

    const int tid  = threadIdx.x;
    const int w    = tid >> 6;        // wave 0..3
    const int lane = tid & 63;
    const int n    = lane & 15;       // batch col
    const int q    = lane >> 4;       // quad -> k-slots 8q..8q+7
    const int b0   = blockIdx.x * 16;

    const float K1 = 1.442695040888963f;   // log2 e
    const float K2 = 2.885390081777927f;   // 2 log2 e

    for (int i = tid; i < 2 * 768; i += 256) ((short*)hb)[i] = 0;

    // ---- A fragments for row-blocks jbA=w, jbB=w+4 (jb=7 all-zero) ----
    // Within a block: MFMA row rr=n -> unit 4*jb + (n>>2), gate n&3.
    // k map: 0..2 w_ih, 3 bias, 4..28 w_hh col k-4, 29..31 pad.
    bf16x8 afA, afB;
    {
        const int g = n & 3, us = n >> 2;
        const int uA = 4 * w + us;            // <= 15, always valid
        const int uB = 4 * (w + 4) + us;      // 16..31, guard < 25
        #pragma unroll
        for (int j = 0; j < 8; ++j) {
            const int k = q * 8 + j;
            float vA = 0.f, vB = 0.f;
            {
                const int orow = g * HSZ + uA;
                if (k < ISZ)            vA = w_ih[orow * ISZ + k];
                else if (k == ISZ)      vA = b_ih[orow] + b_hh[orow];
                else if (k < 4 + HSZ)   vA = w_hh[orow * HSZ + (k - 4)];
                vA *= (g == 2) ? -K2 : -K1;
            }
            if (uB < HSZ) {
                const int orow = g * HSZ + uB;
                if (k < ISZ)            vB = w_ih[orow * ISZ + k];
                else if (k == ISZ)      vB = b_ih[orow] + b_hh[orow];
                else if (k < 4 + HSZ)   vB = w_hh[orow * HSZ + (k - 4)];
                vB *= (g == 2) ? -K2 : -K1;
            }
            afA[j] = (short)bf16_bits(vA);
            afB[j] = (short)bf16_bits(vB);
        }
    }

    // ---- write slots: unit u=4jb+q -> k=u+4 (pads/scrap land harmlessly) --
    const int uwA = 4 * w + q;                 // <= 15
    const int uwB = 4 * (w + 4) + q;           // 16..31 (>=25 -> pad/scrap)
    const int kwA = uwA + 4, kwB = uwB + 4;    // kwB <= 35 -> scrap region
    const int woffA = (kwA >> 3) * 128 + n * 8 + (kwA & 7);
    const int woffB = (kwB >> 3) * 128 + n * 8 + (kwB & 7);
    const int rdoff = lane * 8;

    v2f c = {0.f, 0.f}, h = {0.f, 0.f};

    // ---- x prefetch: 3 x float4 per 4-step group, reg ping-pong ----
    const float* __restrict__ xg = x + (size_t)(b0 + n) * (TSTEPS * ISZ);
    float4 a0 = ((const float4*)xg)[0];
    float4 a1 = ((const float4*)xg)[1];
    float4 a2 = ((const float4*)xg)[2];

    __syncthreads();   // zeros visible (drains first prefetch once - ok)

    // ---- R21: anti-phase injection. One block of each co-resident pair
    // sleeps ~450cy (half of R19's measured 914cy step period) so its
    // issue-dense window covers the partner's chain window thereafter.
    // Parity (bit8 ^ bit0) differs across both plausible pairings.
    if (((blockIdx.x >> 8) ^ blockIdx.x) & 1) {
        asm volatile("s_sleep 7" ::: "memory");
    }

    auto step = [&](int rp, float x0, float x1, float x2) {
        // linear ds_read_b128; q0 lanes insert x/bias from registers
        bf16x8 frag = *(const bf16x8*)&hb[rp][rdoff];
        i32x4 fi = __builtin_bit_cast(i32x4, frag);
        const int px0 = (int)pack_bf16(x0, x1);
        const int px1 = (int)pack_bf16(x2, 1.0f);
        fi[0] = (q == 0) ? px0 : fi[0];
        fi[1] = (q == 0) ? px1 : fi[1];
        frag = __builtin_bit_cast(bf16x8, fi);

        const f32x4 zc = {0.f, 0.f, 0.f, 0.f};
        const f32x4 aA = __builtin_amdgcn_mfma_f32_16x16x32_bf16(afA, frag, zc, 0, 0, 0);
        const f32x4 aB = __builtin_amdgcn_mfma_f32_16x16x32_bf16(afB, frag, zc, 0, 0, 0);

        // acts (prescaled): 14 trans; glue packed v2f across (A,B) blocks
        const v2f e0 = {__builtin_amdgcn_exp2f(aA[0]), __builtin_amdgcn_exp2f(aB[0])};
        const v2f e1 = {__builtin_amdgcn_exp2f(aA[1]), __builtin_amdgcn_exp2f(aB[1])};
        const v2f e2 = {__builtin_amdgcn_exp2f(fminf(aA[2], 126.f)),
                        __builtin_amdgcn_exp2f(fminf(aB[2], 126.f))};
        const v2f e3 = {__builtin_amdgcn_exp2f(aA[3]), __builtin_amdgcn_exp2f(aB[3])};
        const v2f one = {1.f, 1.f};
        const v2f s0 = e0 + one, s1 = e1 + one, s2 = e2 + one, m2 = one - e2;
        const v2f p02 = s0 * s2;
        const v2f num = c * p02 + m2 * s1;     // merged-denominator c-update
        const v2f den = p02 * s1;
        c = num * rcp2(den);
        const v2f ec = {__builtin_amdgcn_exp2f(fminf(-K2 * c.x, 126.f)),
                        __builtin_amdgcn_exp2f(fminf(-K2 * c.y, 126.f))};
        const v2f hden = (e3 + one) * (ec + one);
        h = (one - ec) * rcp2(hden);

        const int wp = rp ^ 1;
        hb[wp][woffA] = (short)bf16_bits(h.x);
        hb[wp][woffB] = (short)bf16_bits(h.y);   // pad/scrap-slot trick
        // retire DS writes, then barrier; vmcnt (x prefetch) stays in flight
        asm volatile("s_waitcnt lgkmcnt(0)" ::: "memory");
        __builtin_amdgcn_s_barrier();
    };

    #pragma unroll 1
    for (int g = 0; g < 128; g += 2) {
        const float4* __restrict__ p1 =
            (const float4*)(xg + (size_t)((g + 1 < 128 ? g + 1 : 127) * 12));
        const float4 n0 = p1[0], n1 = p1[1], n2 = p1[2];
        step(0, a0.x, a0.y, a0.z);
        step(1, a0.w, a1.x, a1.y);
        step(0, a1.z, a1.w, a2.x);
        step(1, a2.y, a2.z, a2.w);
        const float4* __restrict__ p2 =
            (const float4*)(xg + (size_t)((g + 2 < 128 ? g + 2 : 127) * 12));
        a0 = p2[0]; a1 = p2[1]; a2 = p2[2];
        step(0, n0.x, n0.y, n0.z);
        step(1, n0.w, n1.x, n1.y);
        step(0, n1.z, n1.w, n2.x);
        step(1, n2.y, n2.z, n2.w);
    }

    // ---- final linear: out[b] = sum_u w_lin[u]*h[u] + b_lin ----
    const float wlA = (uwA < HSZ) ? w_lin[uwA] : 0.f;
    const float wlB = (uwB < HSZ) ? w_lin[uwB] : 0.f;
    float v = wlA * h.x + wlB * h.y;
    v += __shfl_xor(v, 16);
    v += __shfl_xor(v, 32);
    if (lane < 16) outred[w][lane] = v;
    __syncthreads();
    if (tid < 16) {
        float s = b_lin[0];
        #pragma unroll
        for (int k2 = 0; k2 < 4; ++k2) s += outred[k2][tid];
        out[b0 + tid] = s;
    }
}

extern "C" void kernel_launch(void* const* d_in, const int* in_sizes, int n_in,
                              void* d_out, int out_size, void* d_ws, size_t ws_size,
                              hipStream_t stream) {
    const float* x     = (const float*)d_in[0];
    const float* w_ih  = (const float*)d_in[1];
    const float* w_hh  = (const float*)d_in[2];
    const float* b_ih  = (const float*)d_in[3];
    const float* b_hh  = (const float*)d_in[4];
    const float* w_lin = (const float*)d_in[5];
    const float* b_lin = (const float*)d_in[6];
    float* out = (float*)d_out;

    lstm_mfma<<<8192 / 16, 256, 0, stream>>>(x, w_ih, w_hh, b_ih, b_hh,
                                             w_lin, b_lin, out);
}